// Round 11
// baseline (452.302 us; speedup 1.0000x reference)
//
#include <hip/hip_runtime.h>

#define MDIM 32768
#define NDIM 4096
#define KDIM 1024

typedef __attribute__((ext_vector_type(4))) float floatx4;
typedef __attribute__((ext_vector_type(16))) float float16v;
typedef __attribute__((ext_vector_type(4))) int int4v;
typedef __attribute__((ext_vector_type(8))) int int8v;

// ---- quantize + transpose w: f32 [K,N] -> fp8 e4m3 [N,K] row-major ----
__global__ __launch_bounds__(256) void quant_w_kernel(
    const float* __restrict__ w, char* __restrict__ wT) {
    __shared__ char tile[64][68];
    int nbase = blockIdx.x * 64;
    int kbase = blockIdx.y * 64;
    int t = threadIdx.x;
#pragma unroll
    for (int i = 0; i < 4; ++i) {
        int fidx = t + i * 256;
        int r = fidx >> 4;
        int c4 = fidx & 15;
        floatx4 v = *(const floatx4*)&w[(long)(kbase + r) * NDIM + nbase + c4 * 4];
        int pk = __builtin_amdgcn_cvt_pk_fp8_f32(v.x, v.y, 0, false);
        pk = __builtin_amdgcn_cvt_pk_fp8_f32(v.z, v.w, pk, true);
        *(int*)&tile[r][c4 * 4] = pk;
    }
    __syncthreads();
    int n = t >> 2, kq = (t & 3) * 16;
    int outw[4];
#pragma unroll
    for (int g = 0; g < 4; ++g) {
        int v = 0;
#pragma unroll
        for (int j = 0; j < 4; ++j)
            v |= ((int)(unsigned char)tile[kq + g * 4 + j][n]) << (8 * j);
        outw[g] = v;
    }
    *(int4v*)&wT[(long)(nbase + n) * KDIM + kbase + kq] = *(int4v*)outw;
}

// ======== FUSED GEMM: X f32 [M,K] (quantized in-kernel), BT fp8 [N,K],
// C f32 [M,N]. 256x256 tile, BK=128, 8 K-tiles, 2 bufs (A 32K + B 32K each).
// A: 16x coalesced global_load_dwordx4 fp32 (1 KB/wave/inst) -> cvt_pk_fp8
// -> 16x ds_write_b32 into XOR-swizzled layout (chunk ^= row&7; write-side
// scatter OK for ds_write; 2-way banks = free). B: global_load_lds with
// pre-swizzled source (r6). One barrier/tile; counted VMCNT(12)/(4) so cvt
// frees staging regs in halves; VMCNT(0)+lgkm(0) only pre-barrier (B-GL has
// no dest reg to auto-wait on). bm-major XCD swizzle + NT C-stores (r6 wins).

#define GL(gp, lp)                                                 \
    __builtin_amdgcn_global_load_lds(                              \
        (const __attribute__((address_space(1))) void*)(gp),       \
        (__attribute__((address_space(3))) void*)(lp), 16, 0, 0)

#define VMCNT(n) asm volatile("s_waitcnt vmcnt(" #n ")" ::: "memory")
#define LGKM0    asm volatile("s_waitcnt lgkmcnt(0)" ::: "memory")
#define BARS()  { __builtin_amdgcn_s_barrier(); __builtin_amdgcn_sched_barrier(0); }
#define SP1 __builtin_amdgcn_s_setprio(1)
#define SP0 __builtin_amdgcn_s_setprio(0)

#define MFMA_SC(a_, b_, c_)                                               \
    __builtin_amdgcn_mfma_scale_f32_32x32x64_f8f6f4(                      \
        (a_), (b_), (c_), 0, 0, 0, 0x7F7F7F7F, 0, 0x7F7F7F7F)

__global__ __launch_bounds__(512, 2) void gemm_kernel(
    const float* __restrict__ X, const char* __restrict__ BT,
    const float* __restrict__ bias, float* __restrict__ C) {
    __shared__ char lds[131072];   // buf d: A at d*32768, B at 65536 + d*32768

    const int T = threadIdx.x;
    const int lane = T & 63;
    const int w = T >> 6;            // wave 0..7
    const int wr = w >> 2;           // 0..1 (M)
    const int wc = w & 3;            // 0..3 (N)

    // XCD-aware bijective swizzle, bm-MAJOR: 16 consecutive blocks share one
    // A (x) panel -> fp32 x fetched ~once per XCD into L2.
    const int sw = (blockIdx.x & 7) * 256 + (blockIdx.x >> 3);
    const int bm = (sw >> 4) * 256;
    const int bn = (sw & 15) * 256;

    // ---- B staging via GL (pre-swizzled source; both-sides involution) ----
    const int cs = (T & 7) ^ ((T >> 3) & 7);
    const long bOff = (long)(bn + (T >> 3)) * KDIM + cs * 16;
    const int dstB = (T >> 3) * 128 + (T & 7) * 16;

#define BSTAGE(d_, t_) {                                                      \
        char* lb_ = lds + 65536 + (d_) * 32768 + dstB;                        \
        const char* gb_ = BT + bOff + (t_) * 128;                             \
        GL(gb_, lb_);                 GL(gb_ + 64 * KDIM, lb_ + 8192);        \
        GL(gb_ + 128 * KDIM, lb_ + 16384); GL(gb_ + 192 * KDIM, lb_ + 24576); \
    }

    // ---- A fp32 load base: inst j covers rows (w*32 + j*2 + (lane>>5)),
    // floats (lane&31)*4 -> wave reads 1 KB contiguous (2 rows) per inst.
    const float* xBase = X + (long)(bm + w * 32 + (lane >> 5)) * KDIM + (lane & 31) * 4;
#define A32_H(f_, t_, j0_) { _Pragma("unroll")                                \
        for (int j = 0; j < 8; ++j)                                           \
            f_[j] = *(const floatx4*)(xBase + (long)(j0_ + j) * 2048 + (t_) * 128); }

#define CVT8(dw_, f_) { _Pragma("unroll")                                     \
        for (int j = 0; j < 8; ++j) {                                         \
            int pk_ = __builtin_amdgcn_cvt_pk_fp8_f32(f_[j].x, f_[j].y, 0, false); \
            dw_[j] = __builtin_amdgcn_cvt_pk_fp8_f32(f_[j].z, f_[j].w, pk_, true); } }

    // ---- A ds_write: logical chunk (lane&31)>>2 of row -> phys chunk ^ (row&7).
    const int chnk = (lane & 31) >> 2;
    const int wthn = ((lane & 31) & 3) * 4;
    const int rb = w * 32 + (lane >> 5);
#define DSW8(d_, dw_, j0_) { _Pragma("unroll")                                \
        for (int j = 0; j < 8; ++j) {                                         \
            int row_ = rb + (j0_ + j) * 2;                                    \
            *(int*)(lds + (d_) * 32768 + row_ * 128 +                         \
                    ((chnk ^ (row_ & 7)) << 4) + wthn) = dw_[j]; } }

    // ---- read side (identical to r6) ----
    const int l31 = lane & 31;
    const int kh = lane >> 5;
    const int swz = (l31 & 7) << 4;
    const char* Abase = lds + (wr * 128 + l31) * 128;
    const char* Bbase = lds + 65536 + (wc * 64 + l31) * 128;

    float16v acc[4][2] = {};

#define LD32(dst_, base_, col0_) {                                        \
        int4v lo_ = *(const int4v*)((base_) + (((col0_) + 0) ^ swz));     \
        int4v hi_ = *(const int4v*)((base_) + (((col0_) + 16) ^ swz));    \
        dst_[0] = lo_[0]; dst_[1] = lo_[1]; dst_[2] = lo_[2]; dst_[3] = lo_[3]; \
        dst_[4] = hi_[0]; dst_[5] = hi_[1]; dst_[6] = hi_[2]; dst_[7] = hi_[3]; \
    }

#define CHALF(d_, kk_) {                                                  \
        const char* ap_ = Abase + (d_) * 32768;                           \
        const char* bp_ = Bbase + (d_) * 32768;                           \
        const int col0 = (kk_) * 64 + kh * 32;                            \
        int8v a0, a1, a2, a3, b0, b1;                                     \
        LD32(b0, bp_, col0);          LD32(b1, bp_ + 4096, col0);         \
        LD32(a0, ap_, col0);          LD32(a1, ap_ + 4096, col0);         \
        LD32(a2, ap_ + 8192, col0);   LD32(a3, ap_ + 12288, col0);        \
        SP1;                                                              \
        acc[0][0] = MFMA_SC(a0, b0, acc[0][0]);                           \
        acc[0][1] = MFMA_SC(a0, b1, acc[0][1]);                           \
        acc[1][0] = MFMA_SC(a1, b0, acc[1][0]);                           \
        acc[1][1] = MFMA_SC(a1, b1, acc[1][1]);                           \
        acc[2][0] = MFMA_SC(a2, b0, acc[2][0]);                           \
        acc[2][1] = MFMA_SC(a2, b1, acc[2][1]);                           \
        acc[3][0] = MFMA_SC(a3, b0, acc[3][0]);                           \
        acc[3][1] = MFMA_SC(a3, b1, acc[3][1]);                           \
        SP0;                                                              \
    }

    // Tile t (0..6): stage t+1 (A fp32 reg->cvt->LDS, B GL) around compute t.
#define TILE(c_, t_) {                                                    \
        floatx4 fA[8], fB[8]; int dwA[8], dwB[8];                         \
        A32_H(fA, (t_) + 1, 0);                                           \
        CHALF(c_, 0);                                                     \
        A32_H(fB, (t_) + 1, 8);                                           \
        BSTAGE((c_) ^ 1, (t_) + 1);                                       \
        VMCNT(12);                                                        \
        CVT8(dwA, fA);                                                    \
        CHALF(c_, 1);                                                     \
        VMCNT(4);                                                         \
        CVT8(dwB, fB);                                                    \
        DSW8((c_) ^ 1, dwA, 0); DSW8((c_) ^ 1, dwB, 8);                   \
        VMCNT(0); LGKM0; BARS();                                          \
    }

    // ---- prologue: tile 0 into buf0 ----
    {
        floatx4 fA[8], fB[8]; int dwA[8], dwB[8];
        A32_H(fA, 0, 0); A32_H(fB, 0, 8);
        BSTAGE(0, 0);
        CVT8(dwA, fA); CVT8(dwB, fB);     // data-dep waits
        DSW8(0, dwA, 0); DSW8(0, dwB, 8);
        VMCNT(0); LGKM0; BARS();
    }
    TILE(0, 0); TILE(1, 1); TILE(0, 2); TILE(1, 3);
    TILE(0, 4); TILE(1, 5); TILE(0, 6);
    CHALF(1, 0); CHALF(1, 1);             // tile 7, no staging

    // ---- C write + bias (non-temporal). 32x32 C/D frag:
    // col=lane&31, row=(r&3)+8*(r>>2)+4*kh.
#pragma unroll
    for (int n = 0; n < 2; ++n) {
        int gcol = bn + wc * 64 + n * 32 + l31;
        float bv = bias[gcol];
#pragma unroll
        for (int m = 0; m < 4; ++m) {
            long rbase = bm + wr * 128 + m * 32 + 4 * kh;
#pragma unroll
            for (int r = 0; r < 16; ++r) {
                long grow = rbase + (r & 3) + 8 * (r >> 2);
                __builtin_nontemporal_store(acc[m][n][r] + bv, &C[grow * NDIM + gcol]);
            }
        }
    }
#undef BSTAGE
#undef A32_H
#undef CVT8
#undef DSW8
#undef LD32
#undef CHALF
#undef TILE
}

extern "C" void kernel_launch(void* const* d_in, const int* in_sizes, int n_in,
                              void* d_out, int out_size, void* d_ws, size_t ws_size,
                              hipStream_t stream) {
    (void)in_sizes; (void)n_in; (void)out_size; (void)ws_size;
    const float* x = (const float*)d_in[0];
    const float* wk = (const float*)d_in[1];
    const float* bias = (const float*)d_in[2];
    float* out = (float*)d_out;

    char* wT = (char*)d_ws;                                       // 4 MB

    quant_w_kernel<<<dim3(NDIM / 64, KDIM / 64), 256, 0, stream>>>(wk, wT);
    gemm_kernel<<<2048, 512, 0, stream>>>(x, wT, bias, out);
}

// Round 12
// 318.791 us; speedup vs baseline: 1.4188x; 1.4188x over previous
//
#include <hip/hip_runtime.h>

#define MDIM 32768
#define NDIM 4096
#define KDIM 1024

typedef __attribute__((ext_vector_type(4))) float floatx4;
typedef __attribute__((ext_vector_type(16))) float float16v;
typedef __attribute__((ext_vector_type(4))) int int4v;
typedef __attribute__((ext_vector_type(8))) int int8v;

// ---- quantize x: f32 [M,K] -> fp8 e4m3, FRAG-LINEAR layout ----
// Fragment (m0,k0) = rows m0*32..+31, k bytes k0*64..+63, contiguous 2 KB at
// (m0*16 + k0)*2048; within: (m&31)*64 + (k&63). Reads stay grid-stride
// coalesced (16 consecutive floats/thread); writes are 16 B at 64 B-segment
// granularity (32 MB total - negligible).
__global__ __launch_bounds__(256) void quant_x_kernel(
    const float* __restrict__ x, char* __restrict__ out, int n16) {
    int idx = blockIdx.x * blockDim.x + threadIdx.x;
    int stride = gridDim.x * blockDim.x;
    for (int i = idx; i < n16; i += stride) {
        const floatx4* src = (const floatx4*)(x + (size_t)i * 16);
        int4v o;
#pragma unroll
        for (int j = 0; j < 4; ++j) {
            floatx4 v = __builtin_nontemporal_load(&src[j]);
            int pk = __builtin_amdgcn_cvt_pk_fp8_f32(v.x, v.y, 0, false);
            o[j] = __builtin_amdgcn_cvt_pk_fp8_f32(v.z, v.w, pk, true);
        }
        int m = i >> 6, kq = i & 63;   // k = kq*16
        long addr = (long)((m >> 5) * 16 + (kq >> 2)) * 2048
                  + (m & 31) * 64 + (kq & 3) * 16;
        *(int4v*)(out + addr) = o;
    }
}

// ---- quantize + transpose w: f32 [K,N] -> fp8 e4m3, FRAG-LINEAR (r8) ----
__global__ __launch_bounds__(256) void quant_w_kernel(
    const float* __restrict__ w, char* __restrict__ wT) {
    __shared__ char tile[64][68];
    int nbase = blockIdx.x * 64;
    int kbase = blockIdx.y * 64;
    int t = threadIdx.x;
#pragma unroll
    for (int i = 0; i < 4; ++i) {
        int fidx = t + i * 256;
        int r = fidx >> 4;
        int c4 = fidx & 15;
        floatx4 v = *(const floatx4*)&w[(long)(kbase + r) * NDIM + nbase + c4 * 4];
        int pk = __builtin_amdgcn_cvt_pk_fp8_f32(v.x, v.y, 0, false);
        pk = __builtin_amdgcn_cvt_pk_fp8_f32(v.z, v.w, pk, true);
        *(int*)&tile[r][c4 * 4] = pk;
    }
    __syncthreads();
    int n = t >> 2, kq = (t & 3) * 16;
    int outw[4];
#pragma unroll
    for (int g = 0; g < 4; ++g) {
        int v = 0;
#pragma unroll
        for (int j = 0; j < 4; ++j)
            v |= ((int)(unsigned char)tile[kq + g * 4 + j][n]) << (8 * j);
        outw[g] = v;
    }
    int n0 = blockIdx.x * 2 + (n >> 5);   // abs N / 32
    int k0 = blockIdx.y;                  // abs K / 64
    long addr = (long)(n0 * 16 + k0) * 2048 + (n & 31) * 64 + kq;
    *(int4v*)&wT[addr] = *(int4v*)outw;
}

// ======== GEMM: MX-fp8 (unit scales), ZERO LDS / ZERO BARRIERS.
// A frag-linear [M/32 x K/64 frags], B frag-linear [N/32 x K/64], C f32 [M,N].
// 128x128 tile, 4 waves (2x2), wave tile 64x64 = 2m x 2n frags of 32x32.
// Every operand load = one contiguous global_load_dwordx8 (2 KB/wave) that
// hits L1/L2 (A panel 128 KB shared by 32 bn-neighbors via bm-major swizzle;
// B 4 MB L2-resident). 16 k0-steps, fully unrolled, X/Y register double-
// buffer (1-step prefetch; ~200cy L2 latency << ~1100cy MFMA wall).
// 3 waves/SIMD (launch_bounds(256,3)) -> latency hiding via TLP, and one
// block's NT C-store burst hides under others' MFMA. No stage-barrier tax.

#define MFMA_SC(a_, b_, c_)                                               \
    __builtin_amdgcn_mfma_scale_f32_32x32x64_f8f6f4(                      \
        (a_), (b_), (c_), 0, 0, 0, 0x7F7F7F7F, 0, 0x7F7F7F7F)

__global__ __launch_bounds__(256, 3) void gemm_kernel(
    const char* __restrict__ Aq, const char* __restrict__ Bq,
    const float* __restrict__ bias, float* __restrict__ C) {
    const int T = threadIdx.x;
    const int lane = T & 63;
    const int w = T >> 6;            // wave 0..3
    const int wr = w >> 1;           // 0..1 (M)
    const int wc = w & 1;            // 0..1 (N)

    // XCD-aware bijective swizzle (8192 blocks % 8 == 0), bm-MAJOR within
    // each XCD chunk: 32 consecutive blocks share one A panel (L2-resident).
    const int sw = (blockIdx.x & 7) * 1024 + (blockIdx.x >> 3);
    const int bm = sw >> 5;          // 0..255 (M-block of 128)
    const int bn = sw & 31;          // 0..31  (N-block of 128)

    const int l31 = lane & 31;
    const int kh = lane >> 5;

    // frag (g0, k0) at (g0*16 + k0)*2048; lane byte = l31*64 + kh*32.
    // m-frag g0 = bm*4 + wr*2 + m  (m: +32768); k0: +2048.
    const char* Ab = Aq + (long)(bm * 4 + wr * 2) * 32768 + l31 * 64 + kh * 32;
    const char* Bb = Bq + (long)(bn * 4 + wc * 2) * 32768 + l31 * 64 + kh * 32;

    float16v acc[2][2] = {};

    int8v aX0, aX1, bX0, bX1, aY0, aY1, bY0, bY1;

#define LOADSET(a0_, a1_, b0_, b1_, k0_) {                                \
        a0_ = *(const int8v*)(Ab + (k0_) * 2048);                         \
        a1_ = *(const int8v*)(Ab + 32768 + (k0_) * 2048);                 \
        b0_ = *(const int8v*)(Bb + (k0_) * 2048);                         \
        b1_ = *(const int8v*)(Bb + 32768 + (k0_) * 2048);                 \
    }
#define MFMA4(a0_, a1_, b0_, b1_) {                                       \
        acc[0][0] = MFMA_SC(a0_, b0_, acc[0][0]);                         \
        acc[0][1] = MFMA_SC(a0_, b1_, acc[0][1]);                         \
        acc[1][0] = MFMA_SC(a1_, b0_, acc[1][0]);                         \
        acc[1][1] = MFMA_SC(a1_, b1_, acc[1][1]);                         \
    }

    LOADSET(aX0, aX1, bX0, bX1, 0);
    LOADSET(aY0, aY1, bY0, bY1, 1);  MFMA4(aX0, aX1, bX0, bX1);
    LOADSET(aX0, aX1, bX0, bX1, 2);  MFMA4(aY0, aY1, bY0, bY1);
    LOADSET(aY0, aY1, bY0, bY1, 3);  MFMA4(aX0, aX1, bX0, bX1);
    LOADSET(aX0, aX1, bX0, bX1, 4);  MFMA4(aY0, aY1, bY0, bY1);
    LOADSET(aY0, aY1, bY0, bY1, 5);  MFMA4(aX0, aX1, bX0, bX1);
    LOADSET(aX0, aX1, bX0, bX1, 6);  MFMA4(aY0, aY1, bY0, bY1);
    LOADSET(aY0, aY1, bY0, bY1, 7);  MFMA4(aX0, aX1, bX0, bX1);
    LOADSET(aX0, aX1, bX0, bX1, 8);  MFMA4(aY0, aY1, bY0, bY1);
    LOADSET(aY0, aY1, bY0, bY1, 9);  MFMA4(aX0, aX1, bX0, bX1);
    LOADSET(aX0, aX1, bX0, bX1, 10); MFMA4(aY0, aY1, bY0, bY1);
    LOADSET(aY0, aY1, bY0, bY1, 11); MFMA4(aX0, aX1, bX0, bX1);
    LOADSET(aX0, aX1, bX0, bX1, 12); MFMA4(aY0, aY1, bY0, bY1);
    LOADSET(aY0, aY1, bY0, bY1, 13); MFMA4(aX0, aX1, bX0, bX1);
    LOADSET(aX0, aX1, bX0, bX1, 14); MFMA4(aY0, aY1, bY0, bY1);
    LOADSET(aY0, aY1, bY0, bY1, 15); MFMA4(aX0, aX1, bX0, bX1);
    MFMA4(aY0, aY1, bY0, bY1);

    // ---- C write + bias (non-temporal). 32x32 C/D frag:
    // col=lane&31, row=(r&3)+8*(r>>2)+4*kh.
#pragma unroll
    for (int n = 0; n < 2; ++n) {
        int gcol = bn * 128 + wc * 64 + n * 32 + l31;
        float bv = bias[gcol];
#pragma unroll
        for (int m = 0; m < 2; ++m) {
            long rbase = (long)bm * 128 + wr * 64 + m * 32 + 4 * kh;
#pragma unroll
            for (int r = 0; r < 16; ++r) {
                long grow = rbase + (r & 3) + 8 * (r >> 2);
                __builtin_nontemporal_store(acc[m][n][r] + bv, &C[grow * NDIM + gcol]);
            }
        }
    }
#undef LOADSET
#undef MFMA4
}

extern "C" void kernel_launch(void* const* d_in, const int* in_sizes, int n_in,
                              void* d_out, int out_size, void* d_ws, size_t ws_size,
                              hipStream_t stream) {
    (void)in_sizes; (void)n_in; (void)out_size; (void)ws_size;
    const float* x = (const float*)d_in[0];
    const float* wk = (const float*)d_in[1];
    const float* bias = (const float*)d_in[2];
    float* out = (float*)d_out;

    char* xq = (char*)d_ws;                                       // 32 MB (frag-linear)
    char* wT = (char*)d_ws + (size_t)MDIM * KDIM;                 // 4 MB (frag-linear)

    quant_x_kernel<<<2048, 256, 0, stream>>>(x, xq, MDIM * KDIM / 16);
    quant_w_kernel<<<dim3(NDIM / 64, KDIM / 64), 256, 0, stream>>>(wk, wT);
    gemm_kernel<<<8192, 256, 0, stream>>>(xq, wT, bias, out);
}

// Round 13
// 225.891 us; speedup vs baseline: 2.0023x; 1.4113x over previous
//
#include <hip/hip_runtime.h>

#define MDIM 32768
#define NDIM 4096
#define KDIM 1024

typedef __attribute__((ext_vector_type(4))) float floatx4;
typedef __attribute__((ext_vector_type(16))) float float16v;
typedef __attribute__((ext_vector_type(4))) int int4v;
typedef __attribute__((ext_vector_type(8))) int int8v;

// ---- quantize x: f32 [M,K] -> fp8 e4m3 bytes [M,K] (RNE, saturating) ----
__global__ __launch_bounds__(256) void quant_x_kernel(
    const float* __restrict__ x, char* __restrict__ out, int n16) {
    int idx = blockIdx.x * blockDim.x + threadIdx.x;
    int stride = gridDim.x * blockDim.x;
    const floatx4* xv = (const floatx4*)x;
    int4v* ov = (int4v*)out;
    for (int i = idx; i < n16; i += stride) {
        int4v o;
#pragma unroll
        for (int j = 0; j < 4; ++j) {
            floatx4 v = __builtin_nontemporal_load(&xv[i * 4 + j]);  // x never reused
            int pk = __builtin_amdgcn_cvt_pk_fp8_f32(v.x, v.y, 0, false);
            o[j] = __builtin_amdgcn_cvt_pk_fp8_f32(v.z, v.w, pk, true);
        }
        ov[i] = o;
    }
}

// ---- quantize + transpose w: f32 [K,N] -> fp8 e4m3 [N,K] row-major ----
__global__ __launch_bounds__(256) void quant_w_kernel(
    const float* __restrict__ w, char* __restrict__ wT) {
    __shared__ char tile[64][68];
    int nbase = blockIdx.x * 64;
    int kbase = blockIdx.y * 64;
    int t = threadIdx.x;
#pragma unroll
    for (int i = 0; i < 4; ++i) {
        int fidx = t + i * 256;
        int r = fidx >> 4;
        int c4 = fidx & 15;
        floatx4 v = *(const floatx4*)&w[(long)(kbase + r) * NDIM + nbase + c4 * 4];
        int pk = __builtin_amdgcn_cvt_pk_fp8_f32(v.x, v.y, 0, false);
        pk = __builtin_amdgcn_cvt_pk_fp8_f32(v.z, v.w, pk, true);
        *(int*)&tile[r][c4 * 4] = pk;
    }
    __syncthreads();
    int n = t >> 2, kq = (t & 3) * 16;
    int outw[4];
#pragma unroll
    for (int g = 0; g < 4; ++g) {
        int v = 0;
#pragma unroll
        for (int j = 0; j < 4; ++j)
            v |= ((int)(unsigned char)tile[kq + g * 4 + j][n]) << (8 * j);
        outw[g] = v;
    }
    *(int4v*)&wT[(long)(nbase + n) * KDIM + kbase + kq] = *(int4v*)outw;
}

// ======== GEMM: MX-fp8 (unit scales). A fp8 [M,K], BT fp8 [N,K], C f32 [M,N].
// r6 geometry (256x256 tile, BK=128, 8 K-tiles, 2 bufs A+B, 8 waves 2Mx4N,
// XOR swizzle chunk^=row&7, bm-major XCD swizzle, NT C-stores) with the
// m201-faithful 4-phase interleave: per tile, 4 phases of
//   { ds_read subtile -> 2 staging GLs (next tile) -> s_barrier ->
//     setprio(1) + 4 MFMA + setprio(0) -> s_barrier }
// NO sched_barrier (m141: order-pinning kills), NO manual lgkmcnt (compiler
// emits fine-grained waits). VMCNT(0) folded into the tile-end barrier is
// cheap: with spread issue the youngest GL is >= 1 phase (~1000 cy) old.
// Readers of buf c are gated by the previous tile's VMCNT(0)+barrier.

#define GL(gp, lp)                                                 \
    __builtin_amdgcn_global_load_lds(                              \
        (const __attribute__((address_space(1))) void*)(gp),       \
        (__attribute__((address_space(3))) void*)(lp), 16, 0, 0)

#define VMCNT(n) asm volatile("s_waitcnt vmcnt(" #n ")" ::: "memory")
#define BAR()    __builtin_amdgcn_s_barrier()
#define SP1 __builtin_amdgcn_s_setprio(1)
#define SP0 __builtin_amdgcn_s_setprio(0)

#define MFMA_SC(a_, b_, c_)                                               \
    __builtin_amdgcn_mfma_scale_f32_32x32x64_f8f6f4(                      \
        (a_), (b_), (c_), 0, 0, 0, 0x7F7F7F7F, 0, 0x7F7F7F7F)

__global__ __launch_bounds__(512) void gemm_kernel(
    const char* __restrict__ A, const char* __restrict__ BT,
    const float* __restrict__ bias, float* __restrict__ C) {
    __shared__ char lds[131072];   // buf d: A at d*32768, B at 65536 + d*32768

    const int T = threadIdx.x;
    const int lane = T & 63;
    const int w = T >> 6;            // wave 0..7
    const int wr = w >> 2;           // 0..1 (M)
    const int wc = w & 3;            // 0..3 (N)

    // XCD-aware bijective swizzle (2048 blocks % 8 == 0), bm-MAJOR.
    const int sw = (blockIdx.x & 7) * 256 + (blockIdx.x >> 3);
    const int bm = (sw >> 4) * 256;
    const int bn = (sw & 15) * 256;

    // ---- staging: LDS phys chunk (T&7) of slab-row (T>>3) holds logical
    // chunk (T&7)^((T>>3)&7) (both-sides XOR involution; zero conflicts).
    const int cs = (T & 7) ^ ((T >> 3) & 7);
    const long aOff = (long)(bm + (T >> 3)) * KDIM + cs * 16;
    const long bOff = (long)(bn + (T >> 3)) * KDIM + cs * 16;
    const int dstB = (T >> 3) * 128 + (T & 7) * 16;

    // staging split into 4 GL-pairs (fine interleave, m196/m201)
#define STG_A0(d_, t_) { char* la_ = lds + (d_) * 32768 + dstB;               \
        const char* ga_ = A + aOff + (t_) * 128;                              \
        GL(ga_, la_); GL(ga_ + 64 * KDIM, la_ + 8192); }
#define STG_A1(d_, t_) { char* la_ = lds + (d_) * 32768 + dstB;               \
        const char* ga_ = A + aOff + (t_) * 128;                              \
        GL(ga_ + 128 * KDIM, la_ + 16384); GL(ga_ + 192 * KDIM, la_ + 24576); }
#define STG_B0(d_, t_) { char* lb_ = lds + 65536 + (d_) * 32768 + dstB;       \
        const char* gb_ = BT + bOff + (t_) * 128;                             \
        GL(gb_, lb_); GL(gb_ + 64 * KDIM, lb_ + 8192); }
#define STG_B1(d_, t_) { char* lb_ = lds + 65536 + (d_) * 32768 + dstB;       \
        const char* gb_ = BT + bOff + (t_) * 128;                             \
        GL(gb_ + 128 * KDIM, lb_ + 16384); GL(gb_ + 192 * KDIM, lb_ + 24576); }

    // ---- read-side addresses (identical to r6) ----
    const int l31 = lane & 31;
    const int kh = lane >> 5;
    const int swz = (l31 & 7) << 4;
    const char* Abase = lds + (wr * 128 + l31) * 128;
    const char* Bbase = lds + 65536 + (wc * 64 + l31) * 128;

    float16v acc[4][2] = {};

#define LD32(dst_, base_, col0_) {                                        \
        int4v lo_ = *(const int4v*)((base_) + (((col0_) + 0) ^ swz));     \
        int4v hi_ = *(const int4v*)((base_) + (((col0_) + 16) ^ swz));    \
        dst_[0] = lo_[0]; dst_[1] = lo_[1]; dst_[2] = lo_[2]; dst_[3] = lo_[3]; \
        dst_[4] = hi_[0]; dst_[5] = hi_[1]; dst_[6] = hi_[2]; dst_[7] = hi_[3]; \
    }

    // Tile body: 4 phases. s0..s3 = staging statements (2 GLs each) for the
    // next tile; vm_ = end-of-tile vmcnt gate (VMCNT(0) or nothing).
#define TILE(c_, s0_, s1_, s2_, s3_, vm_) {                               \
        const char* ap_ = Abase + (c_) * 32768;                           \
        const char* bp_ = Bbase + (c_) * 32768;                           \
        int8v a0, a1, a2, a3, b0, b1;                                     \
        /* P0: kk0, m-pair 0 */                                           \
        LD32(b0, bp_, kh * 32);        LD32(b1, bp_ + 4096, kh * 32);     \
        LD32(a0, ap_, kh * 32);        LD32(a1, ap_ + 4096, kh * 32);     \
        s0_;                                                              \
        BAR();                                                            \
        SP1;                                                              \
        acc[0][0] = MFMA_SC(a0, b0, acc[0][0]);                           \
        acc[0][1] = MFMA_SC(a0, b1, acc[0][1]);                           \
        acc[1][0] = MFMA_SC(a1, b0, acc[1][0]);                           \
        acc[1][1] = MFMA_SC(a1, b1, acc[1][1]);                           \
        SP0;                                                              \
        BAR();                                                            \
        /* P1: kk0, m-pair 1 */                                           \
        LD32(a2, ap_ + 8192, kh * 32); LD32(a3, ap_ + 12288, kh * 32);    \
        s1_;                                                              \
        BAR();                                                            \
        SP1;                                                              \
        acc[2][0] = MFMA_SC(a2, b0, acc[2][0]);                           \
        acc[2][1] = MFMA_SC(a2, b1, acc[2][1]);                           \
        acc[3][0] = MFMA_SC(a3, b0, acc[3][0]);                           \
        acc[3][1] = MFMA_SC(a3, b1, acc[3][1]);                           \
        SP0;                                                              \
        BAR();                                                            \
        /* P2: kk1, m-pair 0 */                                           \
        LD32(b0, bp_, 64 + kh * 32);     LD32(b1, bp_ + 4096, 64 + kh * 32); \
        LD32(a0, ap_, 64 + kh * 32);     LD32(a1, ap_ + 4096, 64 + kh * 32); \
        s2_;                                                              \
        BAR();                                                            \
        SP1;                                                              \
        acc[0][0] = MFMA_SC(a0, b0, acc[0][0]);                           \
        acc[0][1] = MFMA_SC(a0, b1, acc[0][1]);                           \
        acc[1][0] = MFMA_SC(a1, b0, acc[1][0]);                           \
        acc[1][1] = MFMA_SC(a1, b1, acc[1][1]);                           \
        SP0;                                                              \
        BAR();                                                            \
        /* P3: kk1, m-pair 1 */                                           \
        LD32(a2, ap_ + 8192, 64 + kh * 32); LD32(a3, ap_ + 12288, 64 + kh * 32); \
        s3_;                                                              \
        BAR();                                                            \
        SP1;                                                              \
        acc[2][0] = MFMA_SC(a2, b0, acc[2][0]);                           \
        acc[2][1] = MFMA_SC(a2, b1, acc[2][1]);                           \
        acc[3][0] = MFMA_SC(a3, b0, acc[3][0]);                           \
        acc[3][1] = MFMA_SC(a3, b1, acc[3][1]);                           \
        SP0;                                                              \
        vm_;                                                              \
        BAR();                                                            \
    }

    // ---- prologue: stage tile 0 into buf 0, gate ----
    STG_A0(0, 0); STG_A1(0, 0); STG_B0(0, 0); STG_B1(0, 0);
    VMCNT(0); BAR();

    // ---- 8 K-tiles; tile t stages t+1 into buf c^1, 2 GLs per phase ----
    TILE(0, STG_A0(1, 1), STG_A1(1, 1), STG_B0(1, 1), STG_B1(1, 1), VMCNT(0));
    TILE(1, STG_A0(0, 2), STG_A1(0, 2), STG_B0(0, 2), STG_B1(0, 2), VMCNT(0));
    TILE(0, STG_A0(1, 3), STG_A1(1, 3), STG_B0(1, 3), STG_B1(1, 3), VMCNT(0));
    TILE(1, STG_A0(0, 4), STG_A1(0, 4), STG_B0(0, 4), STG_B1(0, 4), VMCNT(0));
    TILE(0, STG_A0(1, 5), STG_A1(1, 5), STG_B0(1, 5), STG_B1(1, 5), VMCNT(0));
    TILE(1, STG_A0(0, 6), STG_A1(0, 6), STG_B0(0, 6), STG_B1(0, 6), VMCNT(0));
    TILE(0, STG_A0(1, 7), STG_A1(1, 7), STG_B0(1, 7), STG_B1(1, 7), VMCNT(0));
    TILE(1, (void)0, (void)0, (void)0, (void)0, (void)0);

    // ---- C write + bias (non-temporal). 32x32 C/D frag:
    // col=lane&31, row=(r&3)+8*(r>>2)+4*kh.
#pragma unroll
    for (int n = 0; n < 2; ++n) {
        int gcol = bn + wc * 64 + n * 32 + l31;
        float bv = bias[gcol];
#pragma unroll
        for (int m = 0; m < 4; ++m) {
            long rbase = bm + wr * 128 + m * 32 + 4 * kh;
#pragma unroll
            for (int r = 0; r < 16; ++r) {
                long grow = rbase + (r & 3) + 8 * (r >> 2);
                __builtin_nontemporal_store(acc[m][n][r] + bv, &C[grow * NDIM + gcol]);
            }
        }
    }
#undef STG_A0
#undef STG_A1
#undef STG_B0
#undef STG_B1
#undef TILE
#undef LD32
}

extern "C" void kernel_launch(void* const* d_in, const int* in_sizes, int n_in,
                              void* d_out, int out_size, void* d_ws, size_t ws_size,
                              hipStream_t stream) {
    (void)in_sizes; (void)n_in; (void)out_size; (void)ws_size;
    const float* x = (const float*)d_in[0];
    const float* wk = (const float*)d_in[1];
    const float* bias = (const float*)d_in[2];
    float* out = (float*)d_out;

    char* xq = (char*)d_ws;                                       // 32 MB
    char* wT = (char*)d_ws + (size_t)MDIM * KDIM;                 // 4 MB

    quant_x_kernel<<<2048, 256, 0, stream>>>(x, xq, MDIM * KDIM / 16);
    quant_w_kernel<<<dim3(NDIM / 64, KDIM / 64), 256, 0, stream>>>(wk, wT);
    gemm_kernel<<<2048, 512, 0, stream>>>(xq, wT, bias, out);
}